// Round 1
// baseline (17245.811 us; speedup 1.0000x reference)
//
#include <hip/hip_runtime.h>

// LSTM: S=512, B=64, I=256, H=1024, fp32 in/out.
// Round 5: PERSISTENT kernel. Previous round: 512 dependent launches at ~12.7us/step,
// ~10us/step of which is dispatch overhead (compute is ~1-2us). This round:
//  - one kernel, in-kernel loop over s, device-scope spin barrier (monotonic counter)
//  - weights staged to LDS once per block (40KB), immune to per-step cache invalidates
//  - c-state + biases in registers (thread owns fixed (b,n) across all 512 steps)
//  - x pre-converted to bf16 (prep kernel); x-part MFMAs issued BEFORE barrier wait
//  - grid 256 blocks x 256 thr = 1 block/CU; capacity >= grid -> co-residency guaranteed

#define SEQ   512
#define BATCH 64
#define ISZ   256
#define HID   1024
#define NCOL  4096            // 4 gates * HID; col = n*4 + gate (f,i,g,o)
#define KH    1024
#define KTOT  1280
#define NKS   40              // K-steps of 32
#define NKSH  32              // h-part K-steps

typedef __attribute__((ext_vector_type(8))) short bf16x8;
typedef __attribute__((ext_vector_type(4))) float f32x4;
typedef unsigned short u16;

#define WSW_ELEMS  ((size_t)NCOL * KTOT)        // 5,242,880 bf16 = 10.5 MB
#define XB_ELEMS   ((size_t)SEQ * BATCH * ISZ)  // 8,388,608 bf16 = 16.8 MB
#define HBUF_ELEMS ((size_t)2 * BATCH * HID)    // 131,072 bf16  = 256 KB

__device__ __forceinline__ u16 f2bf(float f) {
    union { float f; unsigned int u; } c; c.f = f;
    unsigned int u = c.u;
    u += 0x7fffu + ((u >> 16) & 1u);            // RNE (inputs finite)
    return (u16)(u >> 16);
}

struct WPtrs { const float* Wh[4]; const float* Wx[4]; };

// Wsw[cg][ks][lane][j]: lane=(q<<4)|nl -> col=cg*16+nl, k=ks*32+q*8+j
__global__ __launch_bounds__(256) void build_w(WPtrs wp, u16* __restrict__ Wsw) {
    size_t did = (size_t)blockIdx.x * 256 + threadIdx.x;    // one 16B group each
    if (did >= WSW_ELEMS / 8) return;
    int lane = (int)(did & 63);
    size_t rest = did >> 6;
    int ks = (int)(rest % NKS);
    int cg = (int)(rest / NKS);
    int nl = lane & 15, q = lane >> 4;
    int col = cg * 16 + nl;
    int g = col & 3, n = col >> 2;
    int k0 = ks * 32 + q * 8;
    const float* src = (k0 < KH) ? wp.Wh[g] + (size_t)n * KH + k0
                                 : wp.Wx[g] + (size_t)n * ISZ + (k0 - KH);
    u16 tmp[8];
#pragma unroll
    for (int j = 0; j < 8; ++j) tmp[j] = f2bf(src[j]);
    *(bf16x8*)(Wsw + did * 8) = *(const bf16x8*)tmp;        // did*16 B, aligned
}

// x fp32 -> bf16 (whole sequence), plus barrier-counter reset for graph replay
__global__ __launch_bounds__(256) void conv_x(const float* __restrict__ x,
                                              u16* __restrict__ xb,
                                              unsigned* __restrict__ cnt) {
    size_t i = (size_t)blockIdx.x * 256 + threadIdx.x;      // one 8-elem group each
    if (i == 0) *cnt = 0;                                   // visible via kernel boundary
    float4 v0 = ((const float4*)x)[i * 2];
    float4 v1 = ((const float4*)x)[i * 2 + 1];
    u16 tmp[8] = { f2bf(v0.x), f2bf(v0.y), f2bf(v0.z), f2bf(v0.w),
                   f2bf(v1.x), f2bf(v1.y), f2bf(v1.z), f2bf(v1.w) };
    *(bf16x8*)(xb + i * 8) = *(const bf16x8*)tmp;
}

struct SeqP {
    const u16* xb;
    const float* bfh; const float* bfx;
    const float* bih; const float* bix;
    const float* bgh; const float* bgx;
    const float* boh; const float* box;
    const u16* Wsw;
    u16* hbuf;        // [2][64][1024] bf16 ring (global, cross-XCD exchanged)
    float* out;       // h_seq, h_final, c_final (fp32)
    unsigned* cnt;    // barrier counter (monotonic; reset by conv_x each replay)
};

__global__ __launch_bounds__(256, 1) void lstm_seq(SeqP p) {
    __shared__ __attribute__((aligned(16))) u16  Wl[NKS * 64 * 8];   // 40 KB B-frags
    __shared__ __attribute__((aligned(16))) float Gsh[4][16][20];    // 5 KB D exchange

    const int t    = threadIdx.x;
    const int lane = t & 63;
    const int w    = t >> 6;             // wave: batch rows w*16..+16
    const int cg   = blockIdx.x;         // col group: cols cg*16..+16
    const int ml   = lane & 15;          // A row / D col index
    const int q    = lane >> 4;          // quad
    const int arow = w * 16 + ml;        // global batch row for A-frags

    // stage this block's weights to LDS once (2560 float4s, 10 per thread)
    {
        const float4* src = (const float4*)(p.Wsw + (size_t)cg * (NKS * 64 * 8));
        float4* dst = (float4*)Wl;
#pragma unroll
        for (int i = 0; i < 10; ++i) dst[t + 256 * i] = src[t + 256 * i];
    }

    // epilogue mapping: thread -> (b = w*16 + lane>>2, n = cg*4 + lane&3), fixed forever
    const int row2 = lane >> 2;
    const int hl   = lane & 3;
    const int bb   = w * 16 + row2;
    const int nn   = cg * 4 + hl;
    const float Bf = p.bfh[nn] + p.bfx[nn];
    const float Bi = p.bih[nn] + p.bix[nn];
    const float Bg = p.bgh[nn] + p.bgx[nn];
    const float Bo = p.boh[nn] + p.box[nn];
    float c = 0.f;                        // cell state lives in a register

    const u16* Wlp = Wl + lane * 8;       // + ks*512 elems
    const unsigned G = gridDim.x;         // 256

    __syncthreads();                      // Wl ready

    for (int s = 0; s < SEQ; ++s) {
        const u16* hrd = p.hbuf + (size_t)(s & 1) * (BATCH * HID);
        u16*       hwr = p.hbuf + (size_t)((s + 1) & 1) * (BATCH * HID);

        f32x4 acc[4] = {{0,0,0,0},{0,0,0,0},{0,0,0,0},{0,0,0,0}};

        // x-part: K = 1024..1279 — independent of h(s-1), overlaps barrier wait
        {
            const u16* Xp = p.xb + ((size_t)s * BATCH + arow) * ISZ + q * 8;
#pragma unroll
            for (int ks = 0; ks < 8; ++ks) {
                bf16x8 a = *(const bf16x8*)(Xp + ks * 32);
                bf16x8 b = *(const bf16x8*)(Wlp + (size_t)(NKSH + ks) * 512);
                acc[ks & 3] = __builtin_amdgcn_mfma_f32_16x16x32_bf16(a, b, acc[ks & 3], 0, 0, 0);
            }
        }

        if (s > 0) {
            // wait: all blocks have published h(s-1)
            if (t == 0) {
                const unsigned tgt = (unsigned)s * G;
                while (__hip_atomic_load(p.cnt, __ATOMIC_RELAXED,
                                         __HIP_MEMORY_SCOPE_AGENT) < tgt)
                    __builtin_amdgcn_s_sleep(1);
            }
            __syncthreads();
            __builtin_amdgcn_fence(__ATOMIC_ACQUIRE, "agent");   // inv stale L1/L2

            // h part: K = 0..1023
            const u16* Ap = hrd + (size_t)arow * HID + q * 8;
#pragma unroll 8
            for (int ks = 0; ks < NKSH; ++ks) {
                bf16x8 a = *(const bf16x8*)(Ap + ks * 32);
                bf16x8 b = *(const bf16x8*)(Wlp + (size_t)ks * 512);
                acc[ks & 3] = __builtin_amdgcn_mfma_f32_16x16x32_bf16(a, b, acc[ks & 3], 0, 0, 0);
            }
        }

        f32x4 av = (acc[0] + acc[1]) + (acc[2] + acc[3]);

        // D layout: col = lane&15, row = q*4+r  (m89-verified)
#pragma unroll
        for (int r = 0; r < 4; ++r) Gsh[w][q * 4 + r][ml] = av[r];
        __syncthreads();
        float4 gv = *(const float4*)&Gsh[w][row2][hl * 4];   // f,i,g,o preacts

        float af = gv.x + Bf;
        float ai = gv.y + Bi;
        float ag = gv.z + Bg;
        float ao = gv.w + Bo;

        float fg = 1.f / (1.f + __expf(-af));
        float ig = 1.f / (1.f + __expf(-ai));
        float gg = 1.f - 2.f / (1.f + __expf(2.f * ag));
        float og = 1.f / (1.f + __expf(-ao));

        c = c * fg + ig * gg;
        float h = (1.f - 2.f / (1.f + __expf(2.f * c))) * og;

        p.out[(size_t)s * (BATCH * HID) + (size_t)bb * HID + nn] = h;
        hwr[(size_t)bb * HID + nn] = f2bf(h);
        if (s == SEQ - 1) {
            p.out[(size_t)SEQ * (BATCH * HID) + (size_t)bb * HID + nn] = h;
            p.out[(size_t)SEQ * (BATCH * HID) + (BATCH * HID) + (size_t)bb * HID + nn] = c;
        }

        // publish h(s): per-wave release (drain stores + L2 writeback), then one arrive
        __builtin_amdgcn_fence(__ATOMIC_RELEASE, "agent");
        __syncthreads();
        if (t == 0)
            __hip_atomic_fetch_add(p.cnt, 1u, __ATOMIC_RELAXED, __HIP_MEMORY_SCOPE_AGENT);
    }
}

extern "C" void kernel_launch(void* const* d_in, const int* in_sizes, int n_in,
                              void* d_out, int out_size, void* d_ws, size_t ws_size,
                              hipStream_t stream) {
    WPtrs wp;
    wp.Wx[0] = (const float*)d_in[1];  wp.Wx[1] = (const float*)d_in[3];
    wp.Wx[2] = (const float*)d_in[5];  wp.Wx[3] = (const float*)d_in[7];
    wp.Wh[0] = (const float*)d_in[9];  wp.Wh[1] = (const float*)d_in[11];
    wp.Wh[2] = (const float*)d_in[13]; wp.Wh[3] = (const float*)d_in[15];

    u16*      Wsw  = (u16*)d_ws;                            // 10.5 MB
    u16*      xb   = Wsw + WSW_ELEMS;                       // 16.8 MB
    u16*      hbuf = xb + XB_ELEMS;                         // 256 KB
    unsigned* cnt  = (unsigned*)(hbuf + HBUF_ELEMS);        // 4 B (16B-aligned)

    SeqP p;
    p.xb   = xb;
    p.bfx  = (const float*)d_in[2];   p.bix  = (const float*)d_in[4];
    p.bgx  = (const float*)d_in[6];   p.box  = (const float*)d_in[8];
    p.bfh  = (const float*)d_in[10];  p.bih  = (const float*)d_in[12];
    p.bgh  = (const float*)d_in[14];  p.boh  = (const float*)d_in[16];
    p.Wsw  = Wsw;
    p.hbuf = hbuf;
    p.out  = (float*)d_out;
    p.cnt  = cnt;

    build_w<<<dim3(2560), 256, 0, stream>>>(wp, Wsw);                    // 655360 groups
    conv_x<<<dim3(4096), 256, 0, stream>>>((const float*)d_in[0], xb, cnt); // 1048576 groups
    lstm_seq<<<dim3(256), 256, 0, stream>>>(p);
}

// Round 2
// 5373.323 us; speedup vs baseline: 3.2095x; 3.2095x over previous
//
#include <hip/hip_runtime.h>

// LSTM: S=512, B=64, I=256, H=1024, fp32 in/out.
// Round 6: persistent kernel WITHOUT agent fences.
// Round-5 failure: per-step fence(release/acquire, agent) = buffer_wbl2 + buffer_inv
// (full L2 writeback+invalidate) x 256 blocks x 512 steps -> 34us/step, 17.2ms.
// This round:
//  - h exchange via agent-scope RELAXED atomics (global_load/store sc1: bypass the
//    non-coherent per-XCD L2, serviced at IF coherence point). No cache maintenance.
//  - ordering: sc1 stores -> s_waitcnt(0) (sc1 store acks from coherence point) ->
//    __syncthreads -> one relaxed flag store per block. Readers poll 128 per-block
//    flags in parallel (no contended fetch_add), workgroup-scope fences only.
//  - 128 blocks x 32 cols (80KB LDS weights): halves the per-step h broadcast
//    (128 x 128KB = 16MB/step from L3) and the barrier participant count.
//  - weights/xb stay L2/LDS-cached forever (no invalidates).

#define SEQ   512
#define BATCH 64
#define ISZ   256
#define HID   1024
#define NCOL  4096            // 4 gates * HID; col = n*4 + gate (f,i,g,o)
#define KH    1024
#define KTOT  1280
#define NKS   40              // K-steps of 32
#define NKSH  32              // h-part K-steps
#define NBLK  128             // persistent blocks (32 cols each)
#define NSUB  2               // two 16-col subgroups per block
#define WSUB  (NKS * 512)     // u16 elems per 16-col subgroup of weights

typedef __attribute__((ext_vector_type(8))) short bf16x8;
typedef __attribute__((ext_vector_type(4))) float f32x4;
typedef unsigned short u16;
typedef unsigned int u32;
typedef unsigned long long u64;

#define WSW_ELEMS  ((size_t)NCOL * KTOT)        // 5,242,880 bf16 = 10.5 MB
#define XB_ELEMS   ((size_t)SEQ * BATCH * ISZ)  // 8,388,608 bf16 = 16.8 MB
#define HBUF_ELEMS ((size_t)2 * BATCH * HID)    // 131,072 bf16  = 256 KB

__device__ __forceinline__ u16 f2bf(float f) {
    union { float f; unsigned int u; } c; c.f = f;
    unsigned int u = c.u;
    u += 0x7fffu + ((u >> 16) & 1u);            // RNE (inputs finite)
    return (u16)(u >> 16);
}

struct WPtrs { const float* Wh[4]; const float* Wx[4]; };

// Wsw[cg][ks][lane][j]: lane=(q<<4)|nl -> col=cg*16+nl, k=ks*32+q*8+j
__global__ __launch_bounds__(256) void build_w(WPtrs wp, u16* __restrict__ Wsw) {
    size_t did = (size_t)blockIdx.x * 256 + threadIdx.x;    // one 16B group each
    if (did >= WSW_ELEMS / 8) return;
    int lane = (int)(did & 63);
    size_t rest = did >> 6;
    int ks = (int)(rest % NKS);
    int cg = (int)(rest / NKS);
    int nl = lane & 15, q = lane >> 4;
    int col = cg * 16 + nl;
    int g = col & 3, n = col >> 2;
    int k0 = ks * 32 + q * 8;
    const float* src = (k0 < KH) ? wp.Wh[g] + (size_t)n * KH + k0
                                 : wp.Wx[g] + (size_t)n * ISZ + (k0 - KH);
    u16 tmp[8];
#pragma unroll
    for (int j = 0; j < 8; ++j) tmp[j] = f2bf(src[j]);
    *(bf16x8*)(Wsw + did * 8) = *(const bf16x8*)tmp;        // did*16 B, aligned
}

// x fp32 -> bf16 (whole sequence) + flag reset for graph replay
__global__ __launch_bounds__(256) void conv_x(const float* __restrict__ x,
                                              u16* __restrict__ xb,
                                              u32* __restrict__ flags) {
    if (blockIdx.x == 0 && threadIdx.x < NBLK)
        __hip_atomic_store(&flags[threadIdx.x], 0u, __ATOMIC_RELAXED,
                           __HIP_MEMORY_SCOPE_AGENT);
    size_t i = (size_t)blockIdx.x * 256 + threadIdx.x;      // one 8-elem group each
    float4 v0 = ((const float4*)x)[i * 2];
    float4 v1 = ((const float4*)x)[i * 2 + 1];
    u16 tmp[8] = { f2bf(v0.x), f2bf(v0.y), f2bf(v0.z), f2bf(v0.w),
                   f2bf(v1.x), f2bf(v1.y), f2bf(v1.z), f2bf(v1.w) };
    *(bf16x8*)(xb + i * 8) = *(const bf16x8*)tmp;
}

struct SeqP {
    const u16* xb;
    const float* bfh; const float* bfx;
    const float* bih; const float* bix;
    const float* bgh; const float* bgx;
    const float* boh; const float* box;
    const u16* Wsw;
    u16* hbuf;        // [2][64][1024] bf16 ring (cross-XCD, accessed via sc1 atomics)
    float* out;       // h_seq, h_final, c_final (fp32)
    u32* flags;       // [NBLK] per-block step counters (monotonic, reset each replay)
};

__global__ __launch_bounds__(256, 1) void lstm_seq(SeqP p) {
    __shared__ __attribute__((aligned(16))) u16   Wl[NSUB * WSUB];   // 80 KB B-frags
    __shared__ __attribute__((aligned(16))) float Gsh[NSUB][4][16][20]; // 10 KB D exch
    __shared__ u16 hsh[BATCH][8];                                    // 1 KB h repack

    const int t    = threadIdx.x;
    const int lane = t & 63;
    const int w    = t >> 6;             // wave: batch rows w*16..+16
    const int cg2  = blockIdx.x;         // block cols: cg2*32..+32
    const int ml   = lane & 15;          // A row / D col index
    const int q    = lane >> 4;          // quad
    const int arow = w * 16 + ml;        // global batch row for A-frags

    // stage this block's weights to LDS once (5120 float4s, 20 per thread)
    {
        const float4* src = (const float4*)(p.Wsw + (size_t)cg2 * (NSUB * WSUB));
        float4* dst = (float4*)Wl;
#pragma unroll
        for (int i = 0; i < 20; ++i) dst[t + 256 * i] = src[t + 256 * i];
    }

    // epilogue mapping: thread -> b = w*16 + lane>>2, n[sub] = cg2*8 + sub*4 + lane&3
    const int row2 = lane >> 2;
    const int hl   = lane & 3;
    const int bb   = w * 16 + row2;
    float Bf[NSUB], Bi[NSUB], Bg[NSUB], Bo[NSUB], c[NSUB];
#pragma unroll
    for (int sub = 0; sub < NSUB; ++sub) {
        int nn = cg2 * 8 + sub * 4 + hl;
        Bf[sub] = p.bfh[nn] + p.bfx[nn];
        Bi[sub] = p.bih[nn] + p.bix[nn];
        Bg[sub] = p.bgh[nn] + p.bgx[nn];
        Bo[sub] = p.boh[nn] + p.box[nn];
        c[sub]  = 0.f;
    }

    const u16* Wlp = Wl + lane * 8;       // + sub*WSUB + ks*512 elems
    union AFrag { u64 d[2]; bf16x8 v; };

    __syncthreads();                      // Wl ready

    for (int s = 0; s < SEQ; ++s) {
        const u16* hrd = p.hbuf + (size_t)(s & 1) * (BATCH * HID);
        u32* hwr32 = (u32*)p.hbuf + (size_t)((s + 1) & 1) * (BATCH * HID / 2);

        f32x4 acc[NSUB][4];
#pragma unroll
        for (int sub = 0; sub < NSUB; ++sub)
#pragma unroll
            for (int j = 0; j < 4; ++j) acc[sub][j] = f32x4{0.f, 0.f, 0.f, 0.f};

        // x-part: K = 1024..1279 — independent of h(s-1), overlaps barrier wait
        {
            const u16* Xp = p.xb + ((size_t)s * BATCH + arow) * ISZ + q * 8;
#pragma unroll
            for (int ks = 0; ks < 8; ++ks) {
                bf16x8 a  = *(const bf16x8*)(Xp + ks * 32);
                bf16x8 b0 = *(const bf16x8*)(Wlp + (size_t)(NKSH + ks) * 512);
                bf16x8 b1 = *(const bf16x8*)(Wlp + WSUB + (size_t)(NKSH + ks) * 512);
                acc[0][ks & 3] = __builtin_amdgcn_mfma_f32_16x16x32_bf16(a, b0, acc[0][ks & 3], 0, 0, 0);
                acc[1][ks & 3] = __builtin_amdgcn_mfma_f32_16x16x32_bf16(a, b1, acc[1][ks & 3], 0, 0, 0);
            }
        }

        if (s > 0) {
            // wait: every block has published h(s-1); 128 threads poll in parallel
            if (t < NBLK) {
                while (__hip_atomic_load(&p.flags[t], __ATOMIC_RELAXED,
                                         __HIP_MEMORY_SCOPE_AGENT) < (u32)s)
                    __builtin_amdgcn_s_sleep(1);
            }
            __syncthreads();
            __builtin_amdgcn_fence(__ATOMIC_ACQUIRE, "workgroup"); // compile-order only

            // h-part: K = 0..1023; A-frags via sc1 loads (bypass stale L2)
            const u64* Ap8 = (const u64*)(hrd + (size_t)arow * HID) + q * 2;
#pragma unroll 8
            for (int ks = 0; ks < NKSH; ++ks) {
                AFrag a;
                a.d[0] = __hip_atomic_load(Ap8 + (size_t)ks * 8,     __ATOMIC_RELAXED, __HIP_MEMORY_SCOPE_AGENT);
                a.d[1] = __hip_atomic_load(Ap8 + (size_t)ks * 8 + 1, __ATOMIC_RELAXED, __HIP_MEMORY_SCOPE_AGENT);
                bf16x8 b0 = *(const bf16x8*)(Wlp + (size_t)ks * 512);
                bf16x8 b1 = *(const bf16x8*)(Wlp + WSUB + (size_t)ks * 512);
                acc[0][ks & 3] = __builtin_amdgcn_mfma_f32_16x16x32_bf16(a.v, b0, acc[0][ks & 3], 0, 0, 0);
                acc[1][ks & 3] = __builtin_amdgcn_mfma_f32_16x16x32_bf16(a.v, b1, acc[1][ks & 3], 0, 0, 0);
            }
        }

        // D layout: col = lane&15, row = q*4+r  (m89-verified)
#pragma unroll
        for (int sub = 0; sub < NSUB; ++sub) {
            f32x4 av = (acc[sub][0] + acc[sub][1]) + (acc[sub][2] + acc[sub][3]);
#pragma unroll
            for (int r = 0; r < 4; ++r) Gsh[sub][w][q * 4 + r][ml] = av[r];
        }
        __syncthreads();

        float hv[NSUB];
#pragma unroll
        for (int sub = 0; sub < NSUB; ++sub) {
            float4 gv = *(const float4*)&Gsh[sub][w][row2][hl * 4]; // f,i,g,o preacts
            float fg = 1.f / (1.f + __expf(-(gv.x + Bf[sub])));
            float ig = 1.f / (1.f + __expf(-(gv.y + Bi[sub])));
            float gg = 1.f - 2.f / (1.f + __expf(2.f * (gv.z + Bg[sub])));
            float og = 1.f / (1.f + __expf(-(gv.w + Bo[sub])));
            c[sub] = c[sub] * fg + ig * gg;
            hv[sub] = (1.f - 2.f / (1.f + __expf(2.f * c[sub]))) * og;
            hsh[bb][sub * 4 + hl] = f2bf(hv[sub]);
        }
        __syncthreads();

        // publish h(s): 256 packed-u32 sc1 stores, drain, one flag store
        {
            int pb = t >> 2, pj = t & 3;
            u32 pk = (u32)hsh[pb][pj * 2] | ((u32)hsh[pb][pj * 2 + 1] << 16);
            __hip_atomic_store(hwr32 + (size_t)pb * (HID / 2) + cg2 * 4 + pj, pk,
                               __ATOMIC_RELAXED, __HIP_MEMORY_SCOPE_AGENT);
        }
        __builtin_amdgcn_fence(__ATOMIC_RELEASE, "workgroup"); // compile-order only
        __builtin_amdgcn_s_waitcnt(0);   // sc1 stores ack'd from coherence point
        __syncthreads();
        if (t == 0)
            __hip_atomic_store(&p.flags[cg2], (u32)(s + 1), __ATOMIC_RELAXED,
                               __HIP_MEMORY_SCOPE_AGENT);

        // outputs (plain stores; visible via kernel-end release)
#pragma unroll
        for (int sub = 0; sub < NSUB; ++sub) {
            int nn = cg2 * 8 + sub * 4 + hl;
            p.out[(size_t)s * (BATCH * HID) + (size_t)bb * HID + nn] = hv[sub];
            if (s == SEQ - 1) {
                p.out[(size_t)SEQ * (BATCH * HID) + (size_t)bb * HID + nn] = hv[sub];
                p.out[(size_t)SEQ * (BATCH * HID) + (BATCH * HID) + (size_t)bb * HID + nn] = c[sub];
            }
        }
    }
}

extern "C" void kernel_launch(void* const* d_in, const int* in_sizes, int n_in,
                              void* d_out, int out_size, void* d_ws, size_t ws_size,
                              hipStream_t stream) {
    WPtrs wp;
    wp.Wx[0] = (const float*)d_in[1];  wp.Wx[1] = (const float*)d_in[3];
    wp.Wx[2] = (const float*)d_in[5];  wp.Wx[3] = (const float*)d_in[7];
    wp.Wh[0] = (const float*)d_in[9];  wp.Wh[1] = (const float*)d_in[11];
    wp.Wh[2] = (const float*)d_in[13]; wp.Wh[3] = (const float*)d_in[15];

    u16* Wsw  = (u16*)d_ws;                                 // 10.5 MB
    u16* xb   = Wsw + WSW_ELEMS;                            // 16.8 MB
    u16* hbuf = xb + XB_ELEMS;                              // 256 KB
    u32* flags = (u32*)(hbuf + HBUF_ELEMS);                 // 512 B

    SeqP p;
    p.xb   = xb;
    p.bfx  = (const float*)d_in[2];   p.bix  = (const float*)d_in[4];
    p.bgx  = (const float*)d_in[6];   p.box  = (const float*)d_in[8];
    p.bfh  = (const float*)d_in[10];  p.bih  = (const float*)d_in[12];
    p.bgh  = (const float*)d_in[14];  p.boh  = (const float*)d_in[16];
    p.Wsw  = Wsw;
    p.hbuf = hbuf;
    p.out  = (float*)d_out;
    p.flags = flags;

    build_w<<<dim3(2560), 256, 0, stream>>>(wp, Wsw);
    conv_x<<<dim3(4096), 256, 0, stream>>>((const float*)d_in[0], xb, flags);
    lstm_seq<<<dim3(NBLK), 256, 0, stream>>>(p);
}

// Round 3
// 3843.849 us; speedup vs baseline: 4.4866x; 1.3979x over previous
//
#include <hip/hip_runtime.h>

// LSTM: S=512, B=64, I=256, H=1024, fp32 in/out.
// Round 7: coalesced cross-XCD exchange.
// Round-6 (5.37ms, 10.5us/step) left MfmaUtil at 2.6% — step time is fabric-dominated:
//  (a) h A-frag loads were 8B x 2KB-stride scattered (2-4x MALL granule over-fetch on a
//      16MB/step broadcast), (b) 128x128 threads hammered a 512B flag region with sc1
//      polls (~260GB/s hot-spot), (c) publish was 4B scattered stores.
// This round (structure otherwise unchanged):
//  - h ring re-tiled [2][blk=128][row=64][n=8]: publish = 1KB contiguous per block
//    (128 coalesced u64 sc1 stores); consumer A-frag (ks,q) = block ks*4+q's region,
//    16 lanes x 256B contiguous. k->n order unchanged => weights need no permutation.
//  - flag poll by wave 0 only: one u64 load per lane covers all 128 flags; block-wide
//    broadcast via the existing __syncthreads.

#define SEQ   512
#define BATCH 64
#define ISZ   256
#define HID   1024
#define NCOL  4096            // 4 gates * HID; col = n*4 + gate (f,i,g,o)
#define KH    1024
#define KTOT  1280
#define NKS   40              // K-steps of 32
#define NKSH  32              // h-part K-steps
#define NBLK  128             // persistent blocks (32 cols = 8 n-values each)
#define NSUB  2               // two 16-col subgroups per block
#define WSUB  (NKS * 512)     // u16 elems per 16-col subgroup of weights

typedef __attribute__((ext_vector_type(8))) short bf16x8;
typedef __attribute__((ext_vector_type(4))) float f32x4;
typedef unsigned short u16;
typedef unsigned int u32;
typedef unsigned long long u64;

#define WSW_ELEMS  ((size_t)NCOL * KTOT)        // 5,242,880 bf16 = 10.5 MB
#define XB_ELEMS   ((size_t)SEQ * BATCH * ISZ)  // 8,388,608 bf16 = 16.8 MB
#define HBUF_ELEMS ((size_t)2 * BATCH * HID)    // 131,072 bf16  = 256 KB

__device__ __forceinline__ u16 f2bf(float f) {
    union { float f; unsigned int u; } c; c.f = f;
    unsigned int u = c.u;
    u += 0x7fffu + ((u >> 16) & 1u);            // RNE (inputs finite)
    return (u16)(u >> 16);
}

struct WPtrs { const float* Wh[4]; const float* Wx[4]; };

// Wsw[cg][ks][lane][j]: lane=(q<<4)|nl -> col=cg*16+nl, k=ks*32+q*8+j
__global__ __launch_bounds__(256) void build_w(WPtrs wp, u16* __restrict__ Wsw) {
    size_t did = (size_t)blockIdx.x * 256 + threadIdx.x;    // one 16B group each
    if (did >= WSW_ELEMS / 8) return;
    int lane = (int)(did & 63);
    size_t rest = did >> 6;
    int ks = (int)(rest % NKS);
    int cg = (int)(rest / NKS);
    int nl = lane & 15, q = lane >> 4;
    int col = cg * 16 + nl;
    int g = col & 3, n = col >> 2;
    int k0 = ks * 32 + q * 8;
    const float* src = (k0 < KH) ? wp.Wh[g] + (size_t)n * KH + k0
                                 : wp.Wx[g] + (size_t)n * ISZ + (k0 - KH);
    u16 tmp[8];
#pragma unroll
    for (int j = 0; j < 8; ++j) tmp[j] = f2bf(src[j]);
    *(bf16x8*)(Wsw + did * 8) = *(const bf16x8*)tmp;        // did*16 B, aligned
}

// x fp32 -> bf16 (whole sequence) + flag reset for graph replay
__global__ __launch_bounds__(256) void conv_x(const float* __restrict__ x,
                                              u16* __restrict__ xb,
                                              u32* __restrict__ flags) {
    if (blockIdx.x == 0 && threadIdx.x < NBLK)
        __hip_atomic_store(&flags[threadIdx.x], 0u, __ATOMIC_RELAXED,
                           __HIP_MEMORY_SCOPE_AGENT);
    size_t i = (size_t)blockIdx.x * 256 + threadIdx.x;      // one 8-elem group each
    float4 v0 = ((const float4*)x)[i * 2];
    float4 v1 = ((const float4*)x)[i * 2 + 1];
    u16 tmp[8] = { f2bf(v0.x), f2bf(v0.y), f2bf(v0.z), f2bf(v0.w),
                   f2bf(v1.x), f2bf(v1.y), f2bf(v1.z), f2bf(v1.w) };
    *(bf16x8*)(xb + i * 8) = *(const bf16x8*)tmp;
}

struct SeqP {
    const u16* xb;
    const float* bfh; const float* bfx;
    const float* bih; const float* bix;
    const float* bgh; const float* bgx;
    const float* boh; const float* box;
    const u16* Wsw;
    u16* hbuf;        // [2][NBLK][64 rows][8 n] bf16 ring (sc1-exchanged, compact)
    float* out;       // h_seq, h_final, c_final (fp32)
    u32* flags;       // [NBLK] per-block step counters (monotonic, reset each replay)
};

__global__ __launch_bounds__(256, 1) void lstm_seq(SeqP p) {
    __shared__ __attribute__((aligned(16))) u16   Wl[NSUB * WSUB];   // 80 KB B-frags
    __shared__ __attribute__((aligned(16))) float Gsh[NSUB][4][16][20]; // 10 KB D exch
    __shared__ __attribute__((aligned(8)))  u16 hsh[BATCH][8];       // 1 KB h repack

    const int t    = threadIdx.x;
    const int lane = t & 63;
    const int w    = t >> 6;             // wave: batch rows w*16..+16
    const int cg2  = blockIdx.x;         // block: cols cg2*32..+32 (n = cg2*8..+8)
    const int ml   = lane & 15;          // A row / D col index
    const int q    = lane >> 4;          // quad
    const int arow = w * 16 + ml;        // global batch row for A-frags

    // stage this block's weights to LDS once (5120 float4s, 20 per thread)
    {
        const float4* src = (const float4*)(p.Wsw + (size_t)cg2 * (NSUB * WSUB));
        float4* dst = (float4*)Wl;
#pragma unroll
        for (int i = 0; i < 20; ++i) dst[t + 256 * i] = src[t + 256 * i];
    }

    // epilogue mapping: thread -> b = w*16 + lane>>2, n[sub] = cg2*8 + sub*4 + lane&3
    const int row2 = lane >> 2;
    const int hl   = lane & 3;
    const int bb   = w * 16 + row2;
    float Bf[NSUB], Bi[NSUB], Bg[NSUB], Bo[NSUB], c[NSUB];
#pragma unroll
    for (int sub = 0; sub < NSUB; ++sub) {
        int nn = cg2 * 8 + sub * 4 + hl;
        Bf[sub] = p.bfh[nn] + p.bfx[nn];
        Bi[sub] = p.bih[nn] + p.bix[nn];
        Bg[sub] = p.bgh[nn] + p.bgx[nn];
        Bo[sub] = p.boh[nn] + p.box[nn];
        c[sub]  = 0.f;
    }

    const u16* Wlp = Wl + lane * 8;       // + sub*WSUB + ks*512 elems
    union AFrag { u64 d[2]; bf16x8 v; };

    __syncthreads();                      // Wl ready

    for (int s = 0; s < SEQ; ++s) {
        const u64* hrd = (const u64*)(p.hbuf + (size_t)(s & 1) * (BATCH * HID));
        u64*       hwr = (u64*)(p.hbuf + (size_t)((s + 1) & 1) * (BATCH * HID));

        f32x4 acc[NSUB][4];
#pragma unroll
        for (int sub = 0; sub < NSUB; ++sub)
#pragma unroll
            for (int j = 0; j < 4; ++j) acc[sub][j] = f32x4{0.f, 0.f, 0.f, 0.f};

        // x-part: K = 1024..1279 — independent of h(s-1), overlaps barrier wait
        {
            const u16* Xp = p.xb + ((size_t)s * BATCH + arow) * ISZ + q * 8;
#pragma unroll
            for (int ks = 0; ks < 8; ++ks) {
                bf16x8 a  = *(const bf16x8*)(Xp + ks * 32);
                bf16x8 b0 = *(const bf16x8*)(Wlp + (size_t)(NKSH + ks) * 512);
                bf16x8 b1 = *(const bf16x8*)(Wlp + WSUB + (size_t)(NKSH + ks) * 512);
                acc[0][ks & 3] = __builtin_amdgcn_mfma_f32_16x16x32_bf16(a, b0, acc[0][ks & 3], 0, 0, 0);
                acc[1][ks & 3] = __builtin_amdgcn_mfma_f32_16x16x32_bf16(a, b1, acc[1][ks & 3], 0, 0, 0);
            }
        }

        if (s > 0) {
            // wait: every block has published h(s-1). Wave 0 polls all 128 flags with
            // one u64 load per lane (minimal coherence-point traffic), then syncthreads
            // broadcasts the arrival to the whole block.
            if (w == 0) {
                const u64* f2 = (const u64*)p.flags + lane;   // flags[2*lane..+2]
                for (;;) {
                    u64 v = __hip_atomic_load(f2, __ATOMIC_RELAXED,
                                              __HIP_MEMORY_SCOPE_AGENT);
                    int ok = ((u32)v >= (u32)s) && ((u32)(v >> 32) >= (u32)s);
                    if (__all(ok)) break;
                    __builtin_amdgcn_s_sleep(2);
                }
            }
            __syncthreads();
            __builtin_amdgcn_fence(__ATOMIC_ACQUIRE, "workgroup"); // compile-order only

            // h-part: K = 0..1023. k = ks*32 + q*8 + j -> producer blk = ks*4+q, nn = j.
            // A-frag = hrd[blk][arow][0..8] : 16 lanes read 256B contiguous.
            const u64* Ap = hrd + (size_t)arow * 2;   // + blk*128 + d
#pragma unroll 8
            for (int ks = 0; ks < NKSH; ++ks) {
                const u64* Ab = Ap + (size_t)(ks * 4 + q) * 128;
                AFrag a;
                a.d[0] = __hip_atomic_load(Ab,     __ATOMIC_RELAXED, __HIP_MEMORY_SCOPE_AGENT);
                a.d[1] = __hip_atomic_load(Ab + 1, __ATOMIC_RELAXED, __HIP_MEMORY_SCOPE_AGENT);
                bf16x8 b0 = *(const bf16x8*)(Wlp + (size_t)ks * 512);
                bf16x8 b1 = *(const bf16x8*)(Wlp + WSUB + (size_t)ks * 512);
                acc[0][ks & 3] = __builtin_amdgcn_mfma_f32_16x16x32_bf16(a.v, b0, acc[0][ks & 3], 0, 0, 0);
                acc[1][ks & 3] = __builtin_amdgcn_mfma_f32_16x16x32_bf16(a.v, b1, acc[1][ks & 3], 0, 0, 0);
            }
        }

        // D layout: col = lane&15, row = q*4+r  (m89-verified)
#pragma unroll
        for (int sub = 0; sub < NSUB; ++sub) {
            f32x4 av = (acc[sub][0] + acc[sub][1]) + (acc[sub][2] + acc[sub][3]);
#pragma unroll
            for (int r = 0; r < 4; ++r) Gsh[sub][w][q * 4 + r][ml] = av[r];
        }
        __syncthreads();

        float hv[NSUB];
#pragma unroll
        for (int sub = 0; sub < NSUB; ++sub) {
            float4 gv = *(const float4*)&Gsh[sub][w][row2][hl * 4]; // f,i,g,o preacts
            float fg = 1.f / (1.f + __expf(-(gv.x + Bf[sub])));
            float ig = 1.f / (1.f + __expf(-(gv.y + Bi[sub])));
            float gg = 1.f - 2.f / (1.f + __expf(2.f * (gv.z + Bg[sub])));
            float og = 1.f / (1.f + __expf(-(gv.w + Bo[sub])));
            c[sub] = c[sub] * fg + ig * gg;
            hv[sub] = (1.f - 2.f / (1.f + __expf(2.f * c[sub]))) * og;
            hsh[bb][sub * 4 + hl] = f2bf(hv[sub]);                  // [row][n] compact
        }
        __syncthreads();

        // publish h(s): block's 1KB region [64 rows][8 n], 128 coalesced u64 sc1 stores
        if (t < 128) {
            u64 v = ((const u64*)hsh)[t];
            __hip_atomic_store(hwr + (size_t)cg2 * 128 + t, v,
                               __ATOMIC_RELAXED, __HIP_MEMORY_SCOPE_AGENT);
        }
        __builtin_amdgcn_fence(__ATOMIC_RELEASE, "workgroup"); // compile-order only
        __builtin_amdgcn_s_waitcnt(0);   // sc1 stores ack'd from coherence point
        __syncthreads();
        if (t == 0)
            __hip_atomic_store(&p.flags[cg2], (u32)(s + 1), __ATOMIC_RELAXED,
                               __HIP_MEMORY_SCOPE_AGENT);

        // outputs (plain stores; visible via kernel-end release)
#pragma unroll
        for (int sub = 0; sub < NSUB; ++sub) {
            int nn = cg2 * 8 + sub * 4 + hl;
            p.out[(size_t)s * (BATCH * HID) + (size_t)bb * HID + nn] = hv[sub];
            if (s == SEQ - 1) {
                p.out[(size_t)SEQ * (BATCH * HID) + (size_t)bb * HID + nn] = hv[sub];
                p.out[(size_t)SEQ * (BATCH * HID) + (BATCH * HID) + (size_t)bb * HID + nn] = c[sub];
            }
        }
    }
}

extern "C" void kernel_launch(void* const* d_in, const int* in_sizes, int n_in,
                              void* d_out, int out_size, void* d_ws, size_t ws_size,
                              hipStream_t stream) {
    WPtrs wp;
    wp.Wx[0] = (const float*)d_in[1];  wp.Wx[1] = (const float*)d_in[3];
    wp.Wx[2] = (const float*)d_in[5];  wp.Wx[3] = (const float*)d_in[7];
    wp.Wh[0] = (const float*)d_in[9];  wp.Wh[1] = (const float*)d_in[11];
    wp.Wh[2] = (const float*)d_in[13]; wp.Wh[3] = (const float*)d_in[15];

    u16* Wsw  = (u16*)d_ws;                                 // 10.5 MB
    u16* xb   = Wsw + WSW_ELEMS;                            // 16.8 MB
    u16* hbuf = xb + XB_ELEMS;                              // 256 KB
    u32* flags = (u32*)(hbuf + HBUF_ELEMS);                 // 512 B

    SeqP p;
    p.xb   = xb;
    p.bfx  = (const float*)d_in[2];   p.bix  = (const float*)d_in[4];
    p.bgx  = (const float*)d_in[6];   p.box  = (const float*)d_in[8];
    p.bfh  = (const float*)d_in[10];  p.bih  = (const float*)d_in[12];
    p.bgh  = (const float*)d_in[14];  p.boh  = (const float*)d_in[16];
    p.Wsw  = Wsw;
    p.hbuf = hbuf;
    p.out  = (float*)d_out;
    p.flags = flags;

    build_w<<<dim3(2560), 256, 0, stream>>>(wp, Wsw);
    conv_x<<<dim3(4096), 256, 0, stream>>>((const float*)d_in[0], xb, flags);
    lstm_seq<<<dim3(NBLK), 256, 0, stream>>>(p);
}